// Round 5
// baseline (714.832 us; speedup 1.0000x reference)
//
#include <hip/hip_runtime.h>
#include <hip/hip_bf16.h>
#include <math.h>
#include <stdint.h>

// ---------- constants ----------
#define C_ 384
#define TOKENS 50176          // B*H*W = 16*56*56 = 16*64*49
#define MTILES 196            // 50176 / 256

typedef __bf16 bf16;
typedef __bf16 bf16x8 __attribute__((ext_vector_type(8)));
typedef __bf16 bf16x4 __attribute__((ext_vector_type(4)));
typedef float  f32x4  __attribute__((ext_vector_type(4)));

__device__ __forceinline__ float b2f(bf16 x) { return (float)x; }
__device__ __forceinline__ bf16  f2b(float x) { return (bf16)x; }

// tanh-form GELU: v * sigmoid(1.5957691 v + 0.0713548 v^3)
__device__ __forceinline__ float fast_gelu(float v) {
    float u2 = v * fmaf(v * v, 0.07135481f, 1.5957691f);
    return v / (1.0f + __expf(-u2));
}

// async global->LDS, 16 bytes per lane. LDS dest must be wave-uniform base + lane*16.
__device__ __forceinline__ void gld_lds16(const bf16* g, bf16* l) {
    __builtin_amdgcn_global_load_lds(
        (const __attribute__((address_space(1))) void*)g,
        (__attribute__((address_space(3))) void*)l, 16, 0, 0);
}

#define SYNC_FENCE() do { __builtin_amdgcn_sched_barrier(0); \
                          __builtin_amdgcn_s_barrier(); \
                          __builtin_amdgcn_sched_barrier(0); } while (0)

// ---------- K0: weight convert+transpose: in f32 [K][N] -> out bf16 [N][K] ----------
__global__ void wtrans_kernel(const float* __restrict__ in, bf16* __restrict__ out,
                              int K, int N) {
    int idx = blockIdx.x * 256 + threadIdx.x;
    if (idx >= K * N) return;
    int n = idx / K, k = idx % K;
    out[idx] = f2b(in[(size_t)k * N + n]);
}

// ---------- K1: LN1 + roll(-3,-3) + window partition. x BCHW f32 -> xw [50176][384] bf16 ----------
__global__ __launch_bounds__(256) void ln1_gather_kernel(
    const float* __restrict__ x, const float* __restrict__ g,
    const float* __restrict__ bt, bf16* __restrict__ xw) {
    int wave = threadIdx.x >> 6, lane = threadIdx.x & 63;
    int T = blockIdx.x * 4 + wave;
    int wi = T / 49, n = T % 49;
    int b = wi >> 6, w64 = wi & 63;
    int bh = w64 >> 3, bw = w64 & 7;
    int hs = bh * 7 + n / 7 + 3; if (hs >= 56) hs -= 56;
    int wsd = bw * 7 + n % 7 + 3; if (wsd >= 56) wsd -= 56;
    const float* xp = x + (size_t)b * C_ * 3136 + hs * 56 + wsd;
    float v[6];
    #pragma unroll
    for (int k = 0; k < 6; k++) v[k] = xp[(size_t)(lane + k * 64) * 3136];
    float s = v[0] + v[1] + v[2] + v[3] + v[4] + v[5];
    #pragma unroll
    for (int m = 32; m; m >>= 1) s += __shfl_xor(s, m);
    float mu = s * (1.0f / 384.0f);
    float s2 = 0.f;
    #pragma unroll
    for (int k = 0; k < 6; k++) { float d = v[k] - mu; s2 += d * d; }
    #pragma unroll
    for (int m = 32; m; m >>= 1) s2 += __shfl_xor(s2, m);
    float rstd = rsqrtf(s2 * (1.0f / 384.0f) + 1e-5f);
    bf16* op = xw + (size_t)T * 384;
    #pragma unroll
    for (int k = 0; k < 6; k++) {
        int c = lane + k * 64;
        op[c] = f2b((v[k] - mu) * rstd * g[c] + bt[c]);
    }
}

enum { EPI_NONE = 0, EPI_GELU = 1, EPI_PROJ = 2, EPI_FC2 = 3 };

// ================= persistent-weight-panel GEMM (K=384 only) ==================
// C[M][N] = A[M][384] @ Wt[N][384]^T + bias. One block owns a 128-wide N-panel:
// its W-panel (128x384 bf16 = 96 KB) is loaded into LDS ONCE, then the block
// loops over a contiguous range of 256-row M-tiles, staging ONLY A (dbuf 32 KB,
// prefetch distance 2, counted vmcnt - never drains). 8 waves = 4M x 2N, each
// 64x64 out. LDS = 160 KiB exactly -> 1 block/CU. Grid = 252 (all-resident).
// Swizzle (verified 0-conflict): granule g at row r holds global granule
// (g&~7)|((g&7)^(r&7)); reads XOR back; row strides (128/768 B) are ==0 mod 128.

__device__ __forceinline__ void stage_A(const bf16* const (&gAs)[4], bf16* dst,
                                        int t, int koff) {
    #pragma unroll
    for (int p = 0; p < 4; p++) gld_lds16(gAs[p] + koff, dst + (p * 512 + t) * 8);
}

__device__ __forceinline__ void compute_step(const bf16* Asb, const bf16* Wsb,
                                             int abase, int wbase, int tkb,
                                             f32x4 (&acc)[4][4]) {
    bf16x8 af[2][4], bw[2][4];
    __builtin_amdgcn_sched_barrier(0);
    #pragma unroll
    for (int i = 0; i < 4; i++) {
        af[0][i] = *(const bf16x8*)((const char*)Asb + abase + i * 2048);
        af[1][i] = *(const bf16x8*)((const char*)Asb + (abase ^ 64) + i * 2048);
    }
    #pragma unroll
    for (int j = 0; j < 4; j++) {
        bw[0][j] = *(const bf16x8*)((const char*)Wsb + wbase + tkb + j * 12288);
        bw[1][j] = *(const bf16x8*)((const char*)Wsb + (wbase ^ 64) + tkb + j * 12288);
    }
    __builtin_amdgcn_sched_barrier(0);
    __builtin_amdgcn_s_setprio(1);
    #pragma unroll
    for (int kk = 0; kk < 2; kk++)
        #pragma unroll
        for (int j = 0; j < 4; j++)
            #pragma unroll
            for (int i = 0; i < 4; i++)
                acc[j][i] = __builtin_amdgcn_mfma_f32_16x16x32_bf16(bw[kk][j], af[kk][i], acc[j][i], 0, 0, 0);
    __builtin_amdgcn_s_setprio(0);
    __builtin_amdgcn_sched_barrier(0);
}

template <int EPI>
__global__ __launch_bounds__(512, 1) void gemm_wp_kernel(
    const bf16* __restrict__ A, const bf16* __restrict__ Wt,
    const float* __restrict__ bias, bf16* __restrict__ Cout,
    int Ndim, int NPANEL, int PPN,
    const float* __restrict__ resx) {   // EPI_PROJ: x in BCHW f32
    __shared__ __align__(16) bf16 As[2][256 * 64];   // 2 x 32 KiB
    __shared__ __align__(16) bf16 Ws[128 * 384];     // 96 KiB
    int t = threadIdx.x;
    int panel = blockIdx.x % NPANEL, pb = blockIdx.x / NPANEL;
    int n0 = panel * 128;
    int lo = (MTILES * pb) / PPN, hi = (MTILES * (pb + 1)) / PPN;
    int ntile = hi - lo;

    // ---- W panel -> LDS (once): 6144 granules, 12 passes ----
    #pragma unroll
    for (int q = 0; q < 12; q++) {
        int idx = q * 512 + t;
        int row = idx / 48, cg = idx % 48;
        int sg = (cg & ~7) | ((cg & 7) ^ (row & 7));   // inverse swizzle on SOURCE
        gld_lds16(Wt + (size_t)(n0 + row) * 384 + sg * 8, &Ws[0] + idx * 8);
    }
    // ---- A staging pointers (current staged m-tile) ----
    const bf16* gAs[4];
    #pragma unroll
    for (int q = 0; q < 4; q++) {
        int idx = q * 512 + t;
        int row = idx >> 3, g = idx & 7;
        int gs = g ^ (row & 7);
        gAs[q] = A + (size_t)(lo * 256 + row) * 384 + gs * 8;
    }
    stage_A(gAs, As[0], t, 0);
    stage_A(gAs, As[1], t, 64);
    int sk = 2;                       // next k-sub (0..5) to stage
    int remaining = ntile * 6 - 2;    // stages left
    asm volatile("s_waitcnt vmcnt(4)" ::: "memory");  // W + A step0 done
    SYNC_FENCE();

    int lane = t & 63, wave = t >> 6;
    int wr = wave >> 1, wc = wave & 1;     // 4M x 2N
    int quad = lane >> 4, lm = lane & 15;
    int g0b = (quad ^ (lm & 7)) * 16;
    int abase = (wr * 64 + lm) * 128 + g0b;
    int wbase = (wc * 64 + lm) * 768 + g0b;
    f32x4 acc[4][4] = {};   // acc[j][i]: n = n0+wc*64+j*16+quad*4+r ; m = wr*64+i*16+lm

    int par = 0;
    for (int lmt = 0; lmt < ntile; ++lmt) {
        #pragma unroll
        for (int tk = 0; tk < 6; ++tk) {
            compute_step(As[par], Ws, abase, wbase, tk * 128, acc);
            if (tk == 5) {
                // ---- epilogue for this m-tile (16 stores -> vmcnt accounting below)
                int m0e = (lo + lmt) * 256;
                #pragma unroll
                for (int i = 0; i < 4; i++) {
                    int m = m0e + wr * 64 + i * 16 + lm;
                    size_t resbase = 0;
                    if (EPI == EPI_PROJ) {
                        int wi = m / 49, n_ = m % 49;
                        int b = wi >> 6, w64 = wi & 63;
                        int bh = w64 >> 3, bw = w64 & 7;
                        int hs = bh * 7 + n_ / 7 + 3; if (hs >= 56) hs -= 56;
                        int wsd = bw * 7 + n_ % 7 + 3; if (wsd >= 56) wsd -= 56;
                        resbase = (size_t)b * C_ * 3136 + hs * 56 + wsd;
                    }
                    #pragma unroll
                    for (int j = 0; j < 4; j++) {
                        int nb = n0 + wc * 64 + j * 16 + quad * 4;
                        f32x4 bj = *(const f32x4*)(bias + nb);
                        f32x4 v;
                        #pragma unroll
                        for (int r = 0; r < 4; r++) v[r] = acc[j][i][r] + bj[r];
                        if (EPI == EPI_GELU) {
                            #pragma unroll
                            for (int r = 0; r < 4; r++) v[r] = fast_gelu(v[r]);
                        }
                        if (EPI == EPI_PROJ) {
                            #pragma unroll
                            for (int r = 0; r < 4; r++) v[r] += resx[resbase + (size_t)(nb + r) * 3136];
                        }
                        bf16x4 o;
                        #pragma unroll
                        for (int r = 0; r < 4; r++) o[r] = f2b(v[r]);
                        *(bf16x4*)(Cout + (size_t)m * Ndim + nb) = o;
                        #pragma unroll
                        for (int r = 0; r < 4; r++) acc[j][i][r] = 0.f;
                    }
                }
            }
            SYNC_FENCE();   // all waves done reading As[par]
            if (remaining > 0) {
                stage_A(gAs, As[par], t, sk * 64);   // stage step s+2 into freed buf
                remaining--;
                if (++sk == 6) {
                    sk = 0;
                    #pragma unroll
                    for (int q = 0; q < 4; q++) gAs[q] += 256 * 384;
                }
                // need step s+1's 4 loads (oldest) done. outstanding <=
                // 4(s+1) + [16 stores if tk==5] + 4(s+2)
                if (tk == 5) asm volatile("s_waitcnt vmcnt(20)" ::: "memory");
                else         asm volatile("s_waitcnt vmcnt(4)"  ::: "memory");
            } else {
                if (tk == 5) asm volatile("s_waitcnt vmcnt(16)" ::: "memory");
                else         asm volatile("s_waitcnt vmcnt(0)"  ::: "memory");
            }
            SYNC_FENCE();   // next buffer ready everywhere
            par ^= 1;
        }
    }
}

// ================= streaming GEMM (round-4 structure) - used for fc2 =========
__device__ __forceinline__ void stage_tile4(const bf16* const (&gA)[4], const bf16* const (&gB)[4],
                                            bf16* Asb, bf16* Bsb, int t, int k0) {
    #pragma unroll
    for (int p = 0; p < 4; p++) gld_lds16(gA[p] + k0, Asb + (p * 256 + t) * 8);
    #pragma unroll
    for (int p = 0; p < 4; p++) gld_lds16(gB[p] + k0, Bsb + (p * 256 + t) * 8);
}

__device__ __forceinline__ void compute_tile4(const bf16* Asb, const bf16* Bsb,
                                              int aoff0, int aoff1, int boff0, int boff1,
                                              f32x4 (&acc)[4][4]) {
    bf16x8 af[2][4], bfr[2][4];
    __builtin_amdgcn_sched_barrier(0);
    #pragma unroll
    for (int i = 0; i < 4; i++) {
        af[0][i] = *(const bf16x8*)((const char*)Asb + aoff0 + i * 2048);
        af[1][i] = *(const bf16x8*)((const char*)Asb + aoff1 + i * 2048);
    }
    #pragma unroll
    for (int j = 0; j < 4; j++) {
        bfr[0][j] = *(const bf16x8*)((const char*)Bsb + boff0 + j * 2048);
        bfr[1][j] = *(const bf16x8*)((const char*)Bsb + boff1 + j * 2048);
    }
    __builtin_amdgcn_sched_barrier(0);
    __builtin_amdgcn_s_setprio(1);
    #pragma unroll
    for (int kk = 0; kk < 2; kk++)
        #pragma unroll
        for (int j = 0; j < 4; j++)
            #pragma unroll
            for (int i = 0; i < 4; i++)
                acc[j][i] = __builtin_amdgcn_mfma_f32_16x16x32_bf16(bfr[kk][j], af[kk][i], acc[j][i], 0, 0, 0);
    __builtin_amdgcn_s_setprio(0);
    __builtin_amdgcn_sched_barrier(0);
}

template <int EPI>
__global__ __launch_bounds__(256, 2) void gemm_kernel(
    const bf16* __restrict__ A, const bf16* __restrict__ Wt,
    const float* __restrict__ bias, bf16* __restrict__ Cout,
    int Kdim, int Ndim,
    const float* __restrict__ resx,
    const bf16* __restrict__ resb) {  // EPI_FC2 : x2 token-major bf16
    __shared__ __align__(16) bf16 As[2][128 * 64];
    __shared__ __align__(16) bf16 Bs[2][128 * 64];
    int t = threadIdx.x;

    int nwg = gridDim.x * gridDim.y;
    int bid = blockIdx.y * gridDim.x + blockIdx.x;
    int q8 = nwg >> 3, r8 = nwg & 7, xcd = bid & 7, off = bid >> 3;
    int swz = (xcd < r8 ? xcd * (q8 + 1) : r8 * (q8 + 1) + (xcd - r8) * q8) + off;
    int n0 = (swz % gridDim.x) * 128;
    int m0 = (swz / gridDim.x) * 128;

    int lane = t & 63, wave = t >> 6;
    int wr = wave >> 1, wc = wave & 1;
    int quad = lane >> 4, lm = lane & 15;
    f32x4 acc[4][4] = {};

    const bf16* gA[4]; const bf16* gB[4];
    #pragma unroll
    for (int p = 0; p < 4; p++) {
        int idx = p * 256 + t;
        int row = idx >> 3, g = idx & 7;
        int gs = g ^ (row & 7);
        gA[p] = A  + (size_t)(m0 + row) * Kdim + gs * 8;
        gB[p] = Wt + (size_t)(n0 + row) * Kdim + gs * 8;
    }

    int g0 = quad ^ (lm & 7);
    int aoff0 = ((wr * 64 + lm) * 64 + g0 * 8) * 2;
    int boff0 = ((wc * 64 + lm) * 64 + g0 * 8) * 2;
    int aoff1 = aoff0 ^ 64;
    int boff1 = boff0 ^ 64;

    int nt = Kdim >> 6;
    stage_tile4(gA, gB, As[0], Bs[0], t, 0);
    stage_tile4(gA, gB, As[1], Bs[1], t, 64);
    asm volatile("s_waitcnt vmcnt(8)" ::: "memory");
    SYNC_FENCE();

    for (int tk = 0; tk < nt; tk += 2) {
        compute_tile4(As[0], Bs[0], aoff0, aoff1, boff0, boff1, acc);
        SYNC_FENCE();
        if (tk + 2 < nt) {
            stage_tile4(gA, gB, As[0], Bs[0], t, (tk + 2) << 6);
            asm volatile("s_waitcnt vmcnt(8)" ::: "memory");
        } else {
            asm volatile("s_waitcnt vmcnt(0)" ::: "memory");
        }
        SYNC_FENCE();
        compute_tile4(As[1], Bs[1], aoff0, aoff1, boff0, boff1, acc);
        if (tk + 2 < nt) {
            SYNC_FENCE();
            if (tk + 3 < nt) {
                stage_tile4(gA, gB, As[1], Bs[1], t, (tk + 3) << 6);
                asm volatile("s_waitcnt vmcnt(8)" ::: "memory");
            } else {
                asm volatile("s_waitcnt vmcnt(0)" ::: "memory");
            }
            SYNC_FENCE();
        }
    }

    #pragma unroll
    for (int i = 0; i < 4; i++) {
        int m = m0 + wr * 64 + i * 16 + lm;
        #pragma unroll
        for (int j = 0; j < 4; j++) {
            int nb = n0 + wc * 64 + j * 16 + quad * 4;
            f32x4 bj = *(const f32x4*)(bias + nb);
            f32x4 v;
            #pragma unroll
            for (int r = 0; r < 4; r++) v[r] = acc[j][i][r] + bj[r];
            if (EPI == EPI_GELU) {
                #pragma unroll
                for (int r = 0; r < 4; r++) v[r] = fast_gelu(v[r]);
            }
            if (EPI == EPI_FC2) {
                bf16x4 rb = *(const bf16x4*)(resb + (size_t)m * 384 + nb);
                #pragma unroll
                for (int r = 0; r < 4; r++) v[r] += b2f(rb[r]);
            }
            bf16x4 o;
            #pragma unroll
            for (int r = 0; r < 4; r++) o[r] = f2b(v[r]);
            *(bf16x4*)(Cout + (size_t)m * Ndim + nb) = o;
        }
    }
}

// ---------- K3: MFMA windowed attention. one wave-block per (window, head) ----------
__global__ __launch_bounds__(64) void attn_mfma_kernel(const bf16* __restrict__ qkv,
                                                       bf16* __restrict__ aout) {
    __shared__ __align__(16) bf16 pbuf[64 * 72];
    __shared__ int reg_[64];
    int l = threadIdx.x;
    int wi = blockIdx.x / 12, h = blockIdx.x % 12;
    int i16 = l & 15, quad = l >> 4;

    {
        int tok = l < 49 ? l : 48;
        int w64 = wi & 63;
        int bh = w64 >> 3, bw = w64 & 7;
        int hh = bh * 7 + tok / 7, ww = bw * 7 + tok % 7;
        int fh = hh < 49 ? 0 : (hh < 53 ? 1 : 2);
        int fw = ww < 49 ? 0 : (ww < 53 ? 1 : 2);
        reg_[l] = fh * 3 + fw;
    }
    __syncthreads();

    const bf16* qbase = qkv + (size_t)wi * 49 * 1152 + h * 32;

    f32x4 s_[4][4] = {};
    bf16x8 af[4], bfr[4];
    #pragma unroll
    for (int mi = 0; mi < 4; mi++) {
        int m = mi * 16 + i16; if (m > 48) m = 48;
        af[mi] = *(const bf16x8*)(qbase + (size_t)m * 1152 + quad * 8);
    }
    #pragma unroll
    for (int nt = 0; nt < 4; nt++) {
        int n = nt * 16 + i16; if (n > 48) n = 48;
        bfr[nt] = *(const bf16x8*)(qbase + 384 + (size_t)n * 1152 + quad * 8);
    }
    #pragma unroll
    for (int mi = 0; mi < 4; mi++)
        #pragma unroll
        for (int nt = 0; nt < 4; nt++)
            s_[mi][nt] = __builtin_amdgcn_mfma_f32_16x16x32_bf16(af[mi], bfr[nt], s_[mi][nt], 0, 0, 0);

    int creg[4];
    #pragma unroll
    for (int nt = 0; nt < 4; nt++) {
        int c = nt * 16 + i16; if (c > 48) c = 48;
        creg[nt] = reg_[c];
    }

    const float scale = 0.17677669529663687f;
    #pragma unroll
    for (int mi = 0; mi < 4; mi++) {
        #pragma unroll
        for (int r = 0; r < 4; r++) {
            int row = mi * 16 + quad * 4 + r;
            int rreg = reg_[row];
            float v[4]; float mx = -1e30f;
            #pragma unroll
            for (int nt = 0; nt < 4; nt++) {
                int c = nt * 16 + i16;
                float x = s_[mi][nt][r] * scale;
                if (c > 48) x = -1e30f;
                else if (rreg != creg[nt]) x -= 100.0f;
                v[nt] = x; mx = fmaxf(mx, x);
            }
            #pragma unroll
            for (int m = 8; m; m >>= 1) mx = fmaxf(mx, __shfl_xor(mx, m));
            float sum = 0.f;
            #pragma unroll
            for (int nt = 0; nt < 4; nt++) { v[nt] = __expf(v[nt] - mx); sum += v[nt]; }
            #pragma unroll
            for (int m = 8; m; m >>= 1) sum += __shfl_xor(sum, m);
            float inv = 1.0f / sum;
            #pragma unroll
            for (int nt = 0; nt < 4; nt++)
                pbuf[row * 72 + nt * 16 + i16] = f2b(v[nt] * inv);
        }
    }
    __syncthreads();

    f32x4 o_[4][2] = {};
    const bf16* vbase = qkv + (size_t)wi * 49 * 1152 + 768 + h * 32;
    #pragma unroll
    for (int ks = 0; ks < 2; ks++) {
        bf16x8 pa[4];
        #pragma unroll
        for (int mi = 0; mi < 4; mi++)
            pa[mi] = *(const bf16x8*)(pbuf + (mi * 16 + i16) * 72 + ks * 32 + quad * 8);
        bf16x8 vb[2];
        #pragma unroll
        for (int nt = 0; nt < 2; nt++)
            #pragma unroll
            for (int j = 0; j < 8; j++) {
                int tok = ks * 32 + quad * 8 + j; if (tok > 48) tok = 48;
                vb[nt][j] = vbase[(size_t)tok * 1152 + nt * 16 + i16];
            }
        #pragma unroll
        for (int mi = 0; mi < 4; mi++)
            #pragma unroll
            for (int nt = 0; nt < 2; nt++)
                o_[mi][nt] = __builtin_amdgcn_mfma_f32_16x16x32_bf16(pa[mi], vb[nt], o_[mi][nt], 0, 0, 0);
    }

    bf16* obase = aout + (size_t)wi * 49 * 384 + h * 32;
    #pragma unroll
    for (int mi = 0; mi < 4; mi++)
        #pragma unroll
        for (int r = 0; r < 4; r++) {
            int row = mi * 16 + quad * 4 + r;
            if (row < 49) {
                #pragma unroll
                for (int nt = 0; nt < 2; nt++)
                    obase[(size_t)row * 384 + nt * 16 + i16] = f2b(o_[mi][nt][r]);
            }
        }
}

// ---------- K5: LN2 on token-major bf16 ----------
__global__ __launch_bounds__(256) void ln2_kernel(const bf16* __restrict__ x2,
                                                  const float* __restrict__ g,
                                                  const float* __restrict__ bt,
                                                  bf16* __restrict__ x2n) {
    int wave = threadIdx.x >> 6, lane = threadIdx.x & 63;
    int T = blockIdx.x * 4 + wave;
    const bf16* xp = x2 + (size_t)T * 384;
    float v[6];
    #pragma unroll
    for (int k = 0; k < 6; k++) v[k] = b2f(xp[lane + k * 64]);
    float s = v[0] + v[1] + v[2] + v[3] + v[4] + v[5];
    #pragma unroll
    for (int m = 32; m; m >>= 1) s += __shfl_xor(s, m);
    float mu = s * (1.0f / 384.0f);
    float s2 = 0.f;
    #pragma unroll
    for (int k = 0; k < 6; k++) { float d = v[k] - mu; s2 += d * d; }
    #pragma unroll
    for (int m = 32; m; m >>= 1) s2 += __shfl_xor(s2, m);
    float rstd = rsqrtf(s2 * (1.0f / 384.0f) + 1e-5f);
    bf16* op = x2n + (size_t)T * 384;
    #pragma unroll
    for (int k = 0; k < 6; k++) {
        int c = lane + k * 64;
        op[c] = f2b((v[k] - mu) * rstd * g[c] + bt[c]);
    }
}

// ---------- K8: window reverse + unshift + transpose to BCHW f32 ----------
__global__ __launch_bounds__(256) void untile_kernel(const bf16* __restrict__ otok,
                                                     float* __restrict__ out) {
    __shared__ float tile[56 * 65];
    int t = threadIdx.x;
    int b = blockIdx.x / 336;
    int rem = blockIdx.x % 336;
    int h = rem / 6;
    int c0 = (rem % 6) * 64;
    int hs = h + 53; if (hs >= 56) hs -= 56;
    int bh = hs / 7, th = hs % 7;
    #pragma unroll
    for (int pass = 0; pass < 14; pass++) {
        int w = pass * 4 + (t >> 6);
        int c = t & 63;
        int wsd = w + 53; if (wsd >= 56) wsd -= 56;
        int T = (b * 64 + bh * 8 + wsd / 7) * 49 + th * 7 + wsd % 7;
        tile[w * 65 + c] = b2f(otok[(size_t)T * 384 + c0 + c]);
    }
    __syncthreads();
    #pragma unroll
    for (int pass = 0; pass < 14; pass++) {
        int idx = pass * 256 + t;
        int c = idx / 56, w = idx % 56;
        out[((size_t)(b * 384 + c0 + c)) * 3136 + h * 56 + w] = tile[w * 65 + c];
    }
}

// ---------- launcher ----------
extern "C" void kernel_launch(void* const* d_in, const int* in_sizes, int n_in,
                              void* d_out, int out_size, void* d_ws, size_t ws_size,
                              hipStream_t stream) {
    (void)in_sizes; (void)n_in; (void)out_size; (void)ws_size;
    const float* x      = (const float*)d_in[0];
    const float* n1g    = (const float*)d_in[1];
    const float* n1b    = (const float*)d_in[2];
    const float* qkv_w  = (const float*)d_in[3];
    const float* qkv_b  = (const float*)d_in[4];
    const float* proj_w = (const float*)d_in[5];
    const float* proj_b = (const float*)d_in[6];
    const float* n2g    = (const float*)d_in[7];
    const float* n2b    = (const float*)d_in[8];
    const float* fc1_w  = (const float*)d_in[9];
    const float* fc1_b  = (const float*)d_in[10];
    const float* fc2_w  = (const float*)d_in[11];
    const float* fc2_b  = (const float*)d_in[12];
    float* out = (float*)d_out;
    char* ws = (char*)d_ws;

    bf16* qkv_wT = (bf16*)(ws + 0);          // 884736 B
    bf16* proj_wT = (bf16*)(ws + 884736);    // 294912 B
    bf16* fc1_wT = (bf16*)(ws + 1179648);    // 1179648 B
    bf16* fc2_wT = (bf16*)(ws + 2359296);    // 1179648 B
    bf16* xw   = (bf16*)(ws + 4194304);      // 38535168 B
    bf16* qkvb = (bf16*)(ws + 42729472);     // 115605504 B
    bf16* attn = (bf16*)(ws + 158334976);    // 38535168 B
    bf16* x2   = (bf16*)(ws + 4194304);      // alias xw (dead)
    bf16* x2n  = (bf16*)(ws + 42729472);     // alias qkv (dead)
    bf16* h1   = (bf16*)(ws + 81264640);     // 154140672 B (overlaps dead attn)
    bf16* otok = (bf16*)(ws + 235405312);    // 38535168 B  (peak ws = 274 MB)

    wtrans_kernel<<<(384 * 1152 + 255) / 256, 256, 0, stream>>>(qkv_w, qkv_wT, 384, 1152);
    wtrans_kernel<<<(384 * 384 + 255) / 256, 256, 0, stream>>>(proj_w, proj_wT, 384, 384);
    wtrans_kernel<<<(384 * 1536 + 255) / 256, 256, 0, stream>>>(fc1_w, fc1_wT, 384, 1536);
    wtrans_kernel<<<(1536 * 384 + 255) / 256, 256, 0, stream>>>(fc2_w, fc2_wT, 1536, 384);

    ln1_gather_kernel<<<TOKENS / 4, 256, 0, stream>>>(x, n1g, n1b, xw);

    // persistent-weight-panel GEMMs (K=384): grid = NPANEL * PPN = 252 blocks
    gemm_wp_kernel<EPI_NONE><<<252, 512, 0, stream>>>(
        xw, qkv_wT, qkv_b, qkvb, 1152, 9, 28, nullptr);

    attn_mfma_kernel<<<12288, 64, 0, stream>>>(qkvb, attn);

    gemm_wp_kernel<EPI_PROJ><<<252, 512, 0, stream>>>(
        attn, proj_wT, proj_b, x2, 384, 3, 84, x);

    ln2_kernel<<<TOKENS / 4, 256, 0, stream>>>(x2, n2g, n2b, x2n);

    gemm_wp_kernel<EPI_GELU><<<252, 512, 0, stream>>>(
        x2n, fc1_wT, fc1_b, h1, 1536, 12, 21, nullptr);

    // fc2 (K=1536, W-panel exceeds LDS): streaming structure (control arm)
    gemm_kernel<EPI_FC2><<<dim3(3, 392), 256, 0, stream>>>(
        h1, fc2_wT, fc2_b, otok, 1536, 384, nullptr, x2);

    untile_kernel<<<16 * 336, 256, 0, stream>>>(otok, out);
}